// Round 6
// baseline (52.856 us; speedup 1.0000x reference)
//
#include <hip/hip_runtime.h>

#define TPL_SIZE 16384
#define TPL_K 16
#define TPL_ND 5
#define TPL_BLK 1024
#define TPL_PTS 2                                  // points per thread
#define TPL_SPAN (TPL_BLK * TPL_PTS)               // 2048 points per block
#define TPL_BPB (TPL_SIZE / TPL_SPAN)              // 8 blocks per batch
#define TPL_CHUNKS (TPL_SIZE / TPL_BLK)            // 16 staging iterations

// 256 blocks x 1024 threads; each block stages the ENTIRE batch table
// (16384 x {px_u16|py_u16<<16, v_f32} = 128 KB) into LDS, then each thread
// solves TWO points (amortizes staging 2x vs R5).
// __launch_bounds__(1024, 4): 16 waves/CU = 4 waves/EU -> 128 VGPR budget.
// R5's unbounded launch_bounds targeted 64 VGPR and spilled the gather
// buffers to scratch (WRITE_SIZE 62 MB!) -- this is the fix.
__global__ __launch_bounds__(TPL_BLK, 4) void tp_lds_kernel(
    const float* __restrict__ x,
    const float* __restrict__ points,
    const int*   __restrict__ edge_index,
    const float* __restrict__ dtp,
    const float* __restrict__ dist,
    const float* __restrict__ weight,
    float* __restrict__ out)
{
    extern __shared__ uint2 lds_pv[];   // [TPL_SIZE] = 128 KB

    const int tid   = threadIdx.x;
    const int blk   = blockIdx.x;
    const int batch = blk / TPL_BPB;
    const int chunk = blk % TPL_BPB;

    const int s0 = chunk * TPL_SPAN + tid;             // point A
    const int s1 = s0 + TPL_BLK;                       // point B
    const size_t row0 = (size_t)batch * TPL_SIZE + s0;
    const size_t row1 = (size_t)batch * TPL_SIZE + s1;

    // ---- issue point A's streaming loads FIRST (hide under staging) ----
    const int4*   eiA = reinterpret_cast<const int4*>(edge_index + row0 * TPL_K);
    const float4* dwA = reinterpret_cast<const float4*>(dist      + row0 * TPL_K);
    int4   ivA0 = eiA[0], ivA1 = eiA[1], ivA2 = eiA[2], ivA3 = eiA[3];
    float4 wvA0 = dwA[0], wvA1 = dwA[1], wvA2 = dwA[2], wvA3 = dwA[3];

    // ---- stage + quantize the whole batch table into LDS (coalesced) ----
    const float2* pb = reinterpret_cast<const float2*>(points) + (size_t)batch * TPL_SIZE;
    const float*  xb = x + (size_t)batch * TPL_SIZE;

    unsigned sxA = 0, syA = 0, sxB = 0, syB = 0;
    float    svA = 0.0f, svB = 0.0f;
    #pragma unroll
    for (int k = 0; k < TPL_CHUNKS; ++k) {
        int i = tid + k * TPL_BLK;
        float2 p = pb[i];
        float  v = xb[i];
        unsigned ux = (unsigned)(p.x * 65536.0f);
        unsigned uy = (unsigned)(p.y * 65536.0f);
        if (ux > 65535u) ux = 65535u;
        if (uy > 65535u) uy = 65535u;
        uint2 e;
        e.x = ux | (uy << 16);
        e.y = __float_as_uint(v);
        lds_pv[i] = e;
        if (k == chunk * TPL_PTS)     { sxA = ux; syA = uy; svA = v; }
        if (k == chunk * TPL_PTS + 1) { sxB = ux; syB = uy; svB = v; }
    }

    // ---- point B's streaming loads: independent of LDS, issue pre-sync ----
    const int4*   eiB = reinterpret_cast<const int4*>(edge_index + row1 * TPL_K);
    const float4* dwB = reinterpret_cast<const float4*>(dist      + row1 * TPL_K);
    int4   ivB0 = eiB[0], ivB1 = eiB[1], ivB2 = eiB[2], ivB3 = eiB[3];
    float4 wvB0 = dwB[0], wvB1 = dwB[1], wvB2 = dwB[2], wvB3 = dwB[3];

    __syncthreads();

    // ================= point A =================
    {
        int ids[TPL_K] = {ivA0.x, ivA0.y, ivA0.z, ivA0.w,
                          ivA1.x, ivA1.y, ivA1.z, ivA1.w,
                          ivA2.x, ivA2.y, ivA2.z, ivA2.w,
                          ivA3.x, ivA3.y, ivA3.z, ivA3.w};
        float wgt[TPL_K] = {wvA0.x, wvA0.y, wvA0.z, wvA0.w,
                            wvA1.x, wvA1.y, wvA1.z, wvA1.w,
                            wvA2.x, wvA2.y, wvA2.z, wvA2.w,
                            wvA3.x, wvA3.y, wvA3.z, wvA3.w};
        uint2 nb[TPL_K];
        #pragma unroll
        for (int t = 0; t < TPL_K; ++t) nb[t] = lds_pv[ids[t] & (TPL_SIZE - 1)];

        float ata[15], atb[TPL_ND];
        #pragma unroll
        for (int i = 0; i < 15; ++i) ata[i] = 0.0f;
        #pragma unroll
        for (int i = 0; i < TPL_ND; ++i) atb[i] = 0.0f;

        #pragma unroll
        for (int t = 0; t < TPL_K; ++t) {
            float w = wgt[t];
            int dxi = (int)(nb[t].x & 0xffffu) - (int)sxA;
            int dyi = (int)(nb[t].x >> 16)     - (int)syA;
            float dx = (float)dxi * 0x1p-16f;
            float dy = (float)dyi * 0x1p-16f;
            float nv = __uint_as_float(nb[t].y);
            float a[TPL_ND];
            a[0] = dx * w;
            a[1] = dy * w;
            a[2] = 0.5f * dx * dx * w;
            a[3] = dx * dy * w;
            a[4] = 0.5f * dy * dy * w;
            float bwv = (nv - svA) * w;
            int c = 0;
            #pragma unroll
            for (int i = 0; i < TPL_ND; ++i) {
                #pragma unroll
                for (int j = i; j < TPL_ND; ++j) ata[c++] += a[i] * a[j];
                atb[i] += a[i] * bwv;
            }
        }

        float M[TPL_ND][TPL_ND], r[TPL_ND];
        {
            int c = 0;
            #pragma unroll
            for (int i = 0; i < TPL_ND; ++i) {
                #pragma unroll
                for (int j = i; j < TPL_ND; ++j) { M[i][j] = ata[c]; M[j][i] = ata[c]; ++c; }
                r[i] = atb[i];
                M[i][i] += 1e-6f;
            }
        }
        #pragma unroll
        for (int i = 0; i < TPL_ND; ++i) {
            float inv = 1.0f / M[i][i];
            #pragma unroll
            for (int j = i + 1; j < TPL_ND; ++j) {
                float f = M[j][i] * inv;
                #pragma unroll
                for (int cc = i + 1; cc < TPL_ND; ++cc) M[j][cc] -= f * M[i][cc];
                r[j] -= f * r[i];
            }
        }
        float sol[TPL_ND];
        #pragma unroll
        for (int i = TPL_ND - 1; i >= 0; --i) {
            float sv2 = r[i];
            #pragma unroll
            for (int cc = i + 1; cc < TPL_ND; ++cc) sv2 -= M[i][cc] * sol[cc];
            sol[i] = sv2 / M[i][i];
        }
        float du = 0.0f;
        #pragma unroll
        for (int i = 0; i < TPL_ND; ++i) du += sol[i] * weight[i];
        out[row0] = svA + dtp[0] * du;
    }

    // ================= point B =================
    {
        int ids[TPL_K] = {ivB0.x, ivB0.y, ivB0.z, ivB0.w,
                          ivB1.x, ivB1.y, ivB1.z, ivB1.w,
                          ivB2.x, ivB2.y, ivB2.z, ivB2.w,
                          ivB3.x, ivB3.y, ivB3.z, ivB3.w};
        float wgt[TPL_K] = {wvB0.x, wvB0.y, wvB0.z, wvB0.w,
                            wvB1.x, wvB1.y, wvB1.z, wvB1.w,
                            wvB2.x, wvB2.y, wvB2.z, wvB2.w,
                            wvB3.x, wvB3.y, wvB3.z, wvB3.w};
        uint2 nb[TPL_K];
        #pragma unroll
        for (int t = 0; t < TPL_K; ++t) nb[t] = lds_pv[ids[t] & (TPL_SIZE - 1)];

        float ata[15], atb[TPL_ND];
        #pragma unroll
        for (int i = 0; i < 15; ++i) ata[i] = 0.0f;
        #pragma unroll
        for (int i = 0; i < TPL_ND; ++i) atb[i] = 0.0f;

        #pragma unroll
        for (int t = 0; t < TPL_K; ++t) {
            float w = wgt[t];
            int dxi = (int)(nb[t].x & 0xffffu) - (int)sxB;
            int dyi = (int)(nb[t].x >> 16)     - (int)syB;
            float dx = (float)dxi * 0x1p-16f;
            float dy = (float)dyi * 0x1p-16f;
            float nv = __uint_as_float(nb[t].y);
            float a[TPL_ND];
            a[0] = dx * w;
            a[1] = dy * w;
            a[2] = 0.5f * dx * dx * w;
            a[3] = dx * dy * w;
            a[4] = 0.5f * dy * dy * w;
            float bwv = (nv - svB) * w;
            int c = 0;
            #pragma unroll
            for (int i = 0; i < TPL_ND; ++i) {
                #pragma unroll
                for (int j = i; j < TPL_ND; ++j) ata[c++] += a[i] * a[j];
                atb[i] += a[i] * bwv;
            }
        }

        float M[TPL_ND][TPL_ND], r[TPL_ND];
        {
            int c = 0;
            #pragma unroll
            for (int i = 0; i < TPL_ND; ++i) {
                #pragma unroll
                for (int j = i; j < TPL_ND; ++j) { M[i][j] = ata[c]; M[j][i] = ata[c]; ++c; }
                r[i] = atb[i];
                M[i][i] += 1e-6f;
            }
        }
        #pragma unroll
        for (int i = 0; i < TPL_ND; ++i) {
            float inv = 1.0f / M[i][i];
            #pragma unroll
            for (int j = i + 1; j < TPL_ND; ++j) {
                float f = M[j][i] * inv;
                #pragma unroll
                for (int cc = i + 1; cc < TPL_ND; ++cc) M[j][cc] -= f * M[i][cc];
                r[j] -= f * r[i];
            }
        }
        float sol[TPL_ND];
        #pragma unroll
        for (int i = TPL_ND - 1; i >= 0; --i) {
            float sv2 = r[i];
            #pragma unroll
            for (int cc = i + 1; cc < TPL_ND; ++cc) sv2 -= M[i][cc] * sol[cc];
            sol[i] = sv2 / M[i][i];
        }
        float du = 0.0f;
        #pragma unroll
        for (int i = 0; i < TPL_ND; ++i) du += sol[i] * weight[i];
        out[row1] = svB + dtp[0] * du;
    }
}

extern "C" void kernel_launch(void* const* d_in, const int* in_sizes, int n_in,
                              void* d_out, int out_size, void* d_ws, size_t ws_size,
                              hipStream_t stream) {
    const float* x          = (const float*)d_in[0];
    const float* points     = (const float*)d_in[1];
    const int*   edge_index = (const int*)d_in[2];
    const float* dtp        = (const float*)d_in[3];
    const float* dist       = (const float*)d_in[4];
    const float* weight     = (const float*)d_in[5];
    float* out = (float*)d_out;

    int total = out_size;                    // B * SIZE = 524288
    int grid  = total / TPL_SPAN;            // 256 blocks (8 per batch)
    size_t lds_bytes = (size_t)TPL_SIZE * sizeof(uint2);  // 128 KB

    tp_lds_kernel<<<grid, TPL_BLK, lds_bytes, stream>>>(
        x, points, edge_index, dtp, dist, weight, out);
}

// Round 7
// 27.450 us; speedup vs baseline: 1.9256x; 1.9256x over previous
//
#include <hip/hip_runtime.h>

#define TPL_SIZE 16384
#define TPL_K 16
#define TPL_ND 5
#define TPL_BLK 512
#define TPL_PTS 4                                  // points per thread
#define TPL_SPAN (TPL_BLK * TPL_PTS)               // 2048 points per block
#define TPL_BPB (TPL_SIZE / TPL_SPAN)              // 8 blocks per batch
#define TPL_ITER (TPL_SIZE / TPL_BLK)              // 32 staging iterations

// 256 blocks x 512 threads. Each block stages its ENTIRE batch table
// (16384 x {px_u16|py_u16<<16, v_f32} = 128 KB) into LDS, then each thread
// solves FOUR points with a 1-deep software pipeline on the edge/dist loads.
//
// Why 512 threads: R5/R6 showed hipcc allocates only 64 VGPRs for
// 1024-thread blocks (WRITE_SIZE 62-89 MB of scratch spill!). 512-thread
// blocks with __launch_bounds__(512,2) get a 256-VGPR budget; LDS (128 KB)
// limits residency to 1 block/CU = 8 waves regardless, so big VGPR is free.
__global__ __launch_bounds__(TPL_BLK, 2) void tp_lds_kernel(
    const float* __restrict__ x,
    const float* __restrict__ points,
    const int*   __restrict__ edge_index,
    const float* __restrict__ dtp,
    const float* __restrict__ dist,
    const float* __restrict__ weight,
    float* __restrict__ out)
{
    extern __shared__ uint2 lds_pv[];   // [TPL_SIZE] = 128 KB

    const int tid   = threadIdx.x;
    const int blk   = blockIdx.x;
    const int batch = blk / TPL_BPB;
    const int chunk = blk % TPL_BPB;

    const size_t base = (size_t)batch * TPL_SIZE + chunk * TPL_SPAN;

    // ---- issue point 0's streaming loads FIRST (latency hides under staging)
    int4   ci[4];
    float4 cw[4];
    {
        const int4*   ei = reinterpret_cast<const int4*>(edge_index + (base + tid) * TPL_K);
        const float4* dw = reinterpret_cast<const float4*>(dist      + (base + tid) * TPL_K);
        ci[0] = ei[0]; ci[1] = ei[1]; ci[2] = ei[2]; ci[3] = ei[3];
        cw[0] = dw[0]; cw[1] = dw[1]; cw[2] = dw[2]; cw[3] = dw[3];
    }

    // ---- stage + quantize the whole batch table into LDS (coalesced) ----
    const float2* pb = reinterpret_cast<const float2*>(points) + (size_t)batch * TPL_SIZE;
    const float*  xb = x + (size_t)batch * TPL_SIZE;

    #pragma unroll
    for (int k = 0; k < TPL_ITER; ++k) {
        int i = tid + k * TPL_BLK;
        float2 p = pb[i];
        float  v = xb[i];
        unsigned ux = (unsigned)(p.x * 65536.0f);
        unsigned uy = (unsigned)(p.y * 65536.0f);
        if (ux > 65535u) ux = 65535u;
        if (uy > 65535u) uy = 65535u;
        uint2 e;
        e.x = ux | (uy << 16);
        e.y = __float_as_uint(v);
        lds_pv[i] = e;
    }
    __syncthreads();

    const float wt0 = weight[0], wt1 = weight[1], wt2 = weight[2],
                wt3 = weight[3], wt4 = weight[4];
    const float dtv = dtp[0];

    #pragma unroll
    for (int p = 0; p < TPL_PTS; ++p) {
        // prefetch next point's edge/dist while computing this one
        int4   ni[4];
        float4 nw[4];
        if (p < TPL_PTS - 1) {
            const size_t rown = base + (p + 1) * TPL_BLK + tid;
            const int4*   ei = reinterpret_cast<const int4*>(edge_index + rown * TPL_K);
            const float4* dw = reinterpret_cast<const float4*>(dist      + rown * TPL_K);
            ni[0] = ei[0]; ni[1] = ei[1]; ni[2] = ei[2]; ni[3] = ei[3];
            nw[0] = dw[0]; nw[1] = dw[1]; nw[2] = dw[2]; nw[3] = dw[3];
        }

        const int    s   = chunk * TPL_SPAN + p * TPL_BLK + tid;
        const size_t row = base + p * TPL_BLK + tid;

        // self point from LDS (same quantization as neighbors)
        uint2 se = lds_pv[s];
        unsigned sx = se.x & 0xffffu;
        unsigned sy = se.x >> 16;
        float    sv = __uint_as_float(se.y);

        int ids[TPL_K] = {ci[0].x, ci[0].y, ci[0].z, ci[0].w,
                          ci[1].x, ci[1].y, ci[1].z, ci[1].w,
                          ci[2].x, ci[2].y, ci[2].z, ci[2].w,
                          ci[3].x, ci[3].y, ci[3].z, ci[3].w};
        float wgt[TPL_K] = {cw[0].x, cw[0].y, cw[0].z, cw[0].w,
                            cw[1].x, cw[1].y, cw[1].z, cw[1].w,
                            cw[2].x, cw[2].y, cw[2].z, cw[2].w,
                            cw[3].x, cw[3].y, cw[3].z, cw[3].w};

        uint2 nb[TPL_K];
        #pragma unroll
        for (int t = 0; t < TPL_K; ++t) nb[t] = lds_pv[ids[t] & (TPL_SIZE - 1)];

        float ata[15], atb[TPL_ND];
        #pragma unroll
        for (int i = 0; i < 15; ++i) ata[i] = 0.0f;
        #pragma unroll
        for (int i = 0; i < TPL_ND; ++i) atb[i] = 0.0f;

        #pragma unroll
        for (int t = 0; t < TPL_K; ++t) {
            float w = wgt[t];
            int dxi = (int)(nb[t].x & 0xffffu) - (int)sx;
            int dyi = (int)(nb[t].x >> 16)     - (int)sy;
            float dx = (float)dxi * 0x1p-16f;
            float dy = (float)dyi * 0x1p-16f;
            float nv = __uint_as_float(nb[t].y);
            float a[TPL_ND];
            a[0] = dx * w;
            a[1] = dy * w;
            a[2] = 0.5f * dx * dx * w;
            a[3] = dx * dy * w;
            a[4] = 0.5f * dy * dy * w;
            float bwv = (nv - sv) * w;
            int c = 0;
            #pragma unroll
            for (int i = 0; i < TPL_ND; ++i) {
                #pragma unroll
                for (int j = i; j < TPL_ND; ++j) ata[c++] += a[i] * a[j];
                atb[i] += a[i] * bwv;
            }
        }

        // 5x5 SPD solve, fully unrolled Gaussian elimination (regs only)
        float M[TPL_ND][TPL_ND], r[TPL_ND];
        {
            int c = 0;
            #pragma unroll
            for (int i = 0; i < TPL_ND; ++i) {
                #pragma unroll
                for (int j = i; j < TPL_ND; ++j) { M[i][j] = ata[c]; M[j][i] = ata[c]; ++c; }
                r[i] = atb[i];
                M[i][i] += 1e-6f;
            }
        }
        #pragma unroll
        for (int i = 0; i < TPL_ND; ++i) {
            float inv = 1.0f / M[i][i];
            #pragma unroll
            for (int j = i + 1; j < TPL_ND; ++j) {
                float f = M[j][i] * inv;
                #pragma unroll
                for (int cc = i + 1; cc < TPL_ND; ++cc) M[j][cc] -= f * M[i][cc];
                r[j] -= f * r[i];
            }
        }
        float sol[TPL_ND];
        #pragma unroll
        for (int i = TPL_ND - 1; i >= 0; --i) {
            float sv2 = r[i];
            #pragma unroll
            for (int cc = i + 1; cc < TPL_ND; ++cc) sv2 -= M[i][cc] * sol[cc];
            sol[i] = sv2 / M[i][i];
        }

        float du = sol[0] * wt0 + sol[1] * wt1 + sol[2] * wt2
                 + sol[3] * wt3 + sol[4] * wt4;
        out[row] = sv + dtv * du;

        // rotate pipeline (static indices only)
        if (p < TPL_PTS - 1) {
            #pragma unroll
            for (int q = 0; q < 4; ++q) { ci[q] = ni[q]; cw[q] = nw[q]; }
        }
    }
}

extern "C" void kernel_launch(void* const* d_in, const int* in_sizes, int n_in,
                              void* d_out, int out_size, void* d_ws, size_t ws_size,
                              hipStream_t stream) {
    const float* x          = (const float*)d_in[0];
    const float* points     = (const float*)d_in[1];
    const int*   edge_index = (const int*)d_in[2];
    const float* dtp        = (const float*)d_in[3];
    const float* dist       = (const float*)d_in[4];
    const float* weight     = (const float*)d_in[5];
    float* out = (float*)d_out;

    int total = out_size;                    // B * SIZE = 524288
    int grid  = total / TPL_SPAN;            // 256 blocks (8 per batch)
    size_t lds_bytes = (size_t)TPL_SIZE * sizeof(uint2);  // 128 KB

    tp_lds_kernel<<<grid, TPL_BLK, lds_bytes, stream>>>(
        x, points, edge_index, dtp, dist, weight, out);
}

// Round 8
// 23.443 us; speedup vs baseline: 2.2547x; 1.1709x over previous
//
#include <hip/hip_runtime.h>

#define TPL_SIZE 16384
#define TPL_K 16
#define TPL_ND 5
#define TPL_BLK 512
#define TPL_PTS 4                                  // points per thread
#define TPL_SPAN (TPL_BLK * TPL_PTS)               // 2048 points per block
#define TPL_BPB (TPL_SIZE / TPL_SPAN)              // 8 blocks per batch
#define TPL_ITER (TPL_SIZE / TPL_BLK)              // 32 staging iterations
#define TPL_NXCD 8

// 256 blocks x 512 threads; each block stages its ENTIRE batch table
// (16384 x {px_u16|py_u16<<16, v_f32} = 128 KB) into LDS, then each thread
// solves FOUR points with a 1-deep software pipeline on the edge/dist loads.
//
// XCD-aware block remap (new in R8): default dispatch round-robins
// consecutive blockIdx across the 8 XCDs, so the 8 chunk-blocks of one
// batch sat on 8 DIFFERENT L2s -- each re-fetched the same 192 KB table
// from HBM (48 MB redundant traffic). Remapping so a batch's 8 blocks share
// blockIdx%8 (= same XCD under round-robin) serves 7 of 8 table reads from
// that XCD's 4 MB L2. Mapping is bijective; if the dispatch assumption is
// wrong this is merely neutral.
__global__ __launch_bounds__(TPL_BLK, 2) void tp_lds_kernel(
    const float* __restrict__ x,
    const float* __restrict__ points,
    const int*   __restrict__ edge_index,
    const float* __restrict__ dtp,
    const float* __restrict__ dist,
    const float* __restrict__ weight,
    float* __restrict__ out)
{
    extern __shared__ uint2 lds_pv[];   // [TPL_SIZE] = 128 KB

    const int tid = threadIdx.x;
    const int blk = blockIdx.x;

    // blk -> (batch, chunk): xcd = blk&7 ; 4 batches per XCD
    const int xcd   = blk & (TPL_NXCD - 1);
    const int batch = xcd * 4 + (blk >> 6);          // [0,32)
    const int chunk = (blk >> 3) & (TPL_BPB - 1);    // [0,8)

    const size_t base = (size_t)batch * TPL_SIZE + chunk * TPL_SPAN;

    // ---- issue point 0's streaming loads FIRST (latency hides under staging)
    int4   ci[4];
    float4 cw[4];
    {
        const int4*   ei = reinterpret_cast<const int4*>(edge_index + (base + tid) * TPL_K);
        const float4* dw = reinterpret_cast<const float4*>(dist      + (base + tid) * TPL_K);
        ci[0] = ei[0]; ci[1] = ei[1]; ci[2] = ei[2]; ci[3] = ei[3];
        cw[0] = dw[0]; cw[1] = dw[1]; cw[2] = dw[2]; cw[3] = dw[3];
    }

    // ---- stage + quantize the whole batch table into LDS (coalesced) ----
    const float2* pb = reinterpret_cast<const float2*>(points) + (size_t)batch * TPL_SIZE;
    const float*  xb = x + (size_t)batch * TPL_SIZE;

    #pragma unroll
    for (int k = 0; k < TPL_ITER; ++k) {
        int i = tid + k * TPL_BLK;
        float2 p = pb[i];
        float  v = xb[i];
        unsigned ux = (unsigned)(p.x * 65536.0f);
        unsigned uy = (unsigned)(p.y * 65536.0f);
        if (ux > 65535u) ux = 65535u;
        if (uy > 65535u) uy = 65535u;
        uint2 e;
        e.x = ux | (uy << 16);
        e.y = __float_as_uint(v);
        lds_pv[i] = e;
    }
    __syncthreads();

    const float wt0 = weight[0], wt1 = weight[1], wt2 = weight[2],
                wt3 = weight[3], wt4 = weight[4];
    const float dtv = dtp[0];

    #pragma unroll
    for (int p = 0; p < TPL_PTS; ++p) {
        // prefetch next point's edge/dist while computing this one
        int4   ni[4];
        float4 nw[4];
        if (p < TPL_PTS - 1) {
            const size_t rown = base + (p + 1) * TPL_BLK + tid;
            const int4*   ei = reinterpret_cast<const int4*>(edge_index + rown * TPL_K);
            const float4* dw = reinterpret_cast<const float4*>(dist      + rown * TPL_K);
            ni[0] = ei[0]; ni[1] = ei[1]; ni[2] = ei[2]; ni[3] = ei[3];
            nw[0] = dw[0]; nw[1] = dw[1]; nw[2] = dw[2]; nw[3] = dw[3];
        }

        const int    s   = chunk * TPL_SPAN + p * TPL_BLK + tid;
        const size_t row = base + p * TPL_BLK + tid;

        // self point from LDS (same quantization as neighbors)
        uint2 se = lds_pv[s];
        unsigned sx = se.x & 0xffffu;
        unsigned sy = se.x >> 16;
        float    sv = __uint_as_float(se.y);

        int ids[TPL_K] = {ci[0].x, ci[0].y, ci[0].z, ci[0].w,
                          ci[1].x, ci[1].y, ci[1].z, ci[1].w,
                          ci[2].x, ci[2].y, ci[2].z, ci[2].w,
                          ci[3].x, ci[3].y, ci[3].z, ci[3].w};
        float wgt[TPL_K] = {cw[0].x, cw[0].y, cw[0].z, cw[0].w,
                            cw[1].x, cw[1].y, cw[1].z, cw[1].w,
                            cw[2].x, cw[2].y, cw[2].z, cw[2].w,
                            cw[3].x, cw[3].y, cw[3].z, cw[3].w};

        uint2 nb[TPL_K];
        #pragma unroll
        for (int t = 0; t < TPL_K; ++t) nb[t] = lds_pv[ids[t] & (TPL_SIZE - 1)];

        float ata[15], atb[TPL_ND];
        #pragma unroll
        for (int i = 0; i < 15; ++i) ata[i] = 0.0f;
        #pragma unroll
        for (int i = 0; i < TPL_ND; ++i) atb[i] = 0.0f;

        #pragma unroll
        for (int t = 0; t < TPL_K; ++t) {
            float w = wgt[t];
            int dxi = (int)(nb[t].x & 0xffffu) - (int)sx;
            int dyi = (int)(nb[t].x >> 16)     - (int)sy;
            float dx = (float)dxi * 0x1p-16f;
            float dy = (float)dyi * 0x1p-16f;
            float nv = __uint_as_float(nb[t].y);
            float a[TPL_ND];
            a[0] = dx * w;
            a[1] = dy * w;
            a[2] = 0.5f * dx * dx * w;
            a[3] = dx * dy * w;
            a[4] = 0.5f * dy * dy * w;
            float bwv = (nv - sv) * w;
            int c = 0;
            #pragma unroll
            for (int i = 0; i < TPL_ND; ++i) {
                #pragma unroll
                for (int j = i; j < TPL_ND; ++j) ata[c++] += a[i] * a[j];
                atb[i] += a[i] * bwv;
            }
        }

        // 5x5 SPD solve, fully unrolled Gaussian elimination (regs only)
        float M[TPL_ND][TPL_ND], r[TPL_ND];
        {
            int c = 0;
            #pragma unroll
            for (int i = 0; i < TPL_ND; ++i) {
                #pragma unroll
                for (int j = i; j < TPL_ND; ++j) { M[i][j] = ata[c]; M[j][i] = ata[c]; ++c; }
                r[i] = atb[i];
                M[i][i] += 1e-6f;
            }
        }
        #pragma unroll
        for (int i = 0; i < TPL_ND; ++i) {
            float inv = 1.0f / M[i][i];
            #pragma unroll
            for (int j = i + 1; j < TPL_ND; ++j) {
                float f = M[j][i] * inv;
                #pragma unroll
                for (int cc = i + 1; cc < TPL_ND; ++cc) M[j][cc] -= f * M[i][cc];
                r[j] -= f * r[i];
            }
        }
        float sol[TPL_ND];
        #pragma unroll
        for (int i = TPL_ND - 1; i >= 0; --i) {
            float sv2 = r[i];
            #pragma unroll
            for (int cc = i + 1; cc < TPL_ND; ++cc) sv2 -= M[i][cc] * sol[cc];
            sol[i] = sv2 / M[i][i];
        }

        float du = sol[0] * wt0 + sol[1] * wt1 + sol[2] * wt2
                 + sol[3] * wt3 + sol[4] * wt4;
        out[row] = sv + dtv * du;

        // rotate pipeline (static indices only)
        if (p < TPL_PTS - 1) {
            #pragma unroll
            for (int q = 0; q < 4; ++q) { ci[q] = ni[q]; cw[q] = nw[q]; }
        }
    }
}

extern "C" void kernel_launch(void* const* d_in, const int* in_sizes, int n_in,
                              void* d_out, int out_size, void* d_ws, size_t ws_size,
                              hipStream_t stream) {
    const float* x          = (const float*)d_in[0];
    const float* points     = (const float*)d_in[1];
    const int*   edge_index = (const int*)d_in[2];
    const float* dtp        = (const float*)d_in[3];
    const float* dist       = (const float*)d_in[4];
    const float* weight     = (const float*)d_in[5];
    float* out = (float*)d_out;

    int total = out_size;                    // B * SIZE = 524288
    int grid  = total / TPL_SPAN;            // 256 blocks (8 per batch)
    size_t lds_bytes = (size_t)TPL_SIZE * sizeof(uint2);  // 128 KB

    tp_lds_kernel<<<grid, TPL_BLK, lds_bytes, stream>>>(
        x, points, edge_index, dtp, dist, weight, out);
}